// Round 7
// baseline (857.545 us; speedup 1.0000x reference)
//
#include <hip/hip_runtime.h>
#include <hip/hip_bf16.h>

#define NNODES 50000
#define NEDGES 600000
#define NGRAPHS 128
#define EMB 128
#define NLAYERS 5
#define BN_EPS 1e-5f
#define SCAN_BLOCKS ((NNODES + 255) / 256)  // 196

typedef short s16x8 __attribute__((ext_vector_type(8)));
typedef float f32x4 __attribute__((ext_vector_type(4)));

__device__ __forceinline__ short f2bf(float f) {
    unsigned u = __builtin_bit_cast(unsigned, f);
    unsigned r = (u + 0x7fffu + ((u >> 16) & 1u)) >> 16;  // RNE
    return (short)r;
}
__device__ __forceinline__ float bf2f(short s) {
    return __builtin_bit_cast(float, ((unsigned)(unsigned short)s) << 16);
}

// ---------------- deg histogram (int atomics only) ---------------------------
__global__ __launch_bounds__(256) void deg_kernel(const int* __restrict__ ei,
                                                  int* __restrict__ deg) {
    int e = blockIdx.x * 256 + threadIdx.x;
    if (e >= NEDGES) return;
    atomicAdd(&deg[ei[NEDGES + e]], 1);
}

// ---------------- multi-block scan ------------------------------------------
__global__ __launch_bounds__(256) void scan1(const int* __restrict__ deg,
                                             int* __restrict__ local_excl,
                                             int* __restrict__ part) {
    __shared__ int sh[256];
    int t = threadIdx.x;
    int i = blockIdx.x * 256 + t;
    int v = (i < NNODES) ? deg[i] : 0;
    sh[t] = v;
    __syncthreads();
    for (int off = 1; off < 256; off <<= 1) {
        int u = (t >= off) ? sh[t - off] : 0;
        __syncthreads();
        sh[t] += u;
        __syncthreads();
    }
    if (i < NNODES) local_excl[i] = sh[t] - v;
    if (t == 255) part[blockIdx.x] = sh[255];
}

__global__ __launch_bounds__(256) void scan2(int* __restrict__ part,
                                             int* __restrict__ blockoff,
                                             int* __restrict__ rowptr) {
    __shared__ int sh[256];
    int t = threadIdx.x;
    int v = (t < SCAN_BLOCKS) ? part[t] : 0;
    sh[t] = v;
    __syncthreads();
    for (int off = 1; off < 256; off <<= 1) {
        int u = (t >= off) ? sh[t - off] : 0;
        __syncthreads();
        sh[t] += u;
        __syncthreads();
    }
    if (t < SCAN_BLOCKS) blockoff[t] = sh[t] - v;
    if (t == 255) rowptr[NNODES] = sh[255];
}

__global__ __launch_bounds__(256) void scan3(const int* __restrict__ local_excl,
                                             const int* __restrict__ blockoff,
                                             int* __restrict__ rowptr,
                                             int* __restrict__ cursor) {
    int i = blockIdx.x * 256 + threadIdx.x;
    if (i >= NNODES) return;
    int v = local_excl[i] + blockoff[blockIdx.x];
    rowptr[i] = v;
    cursor[i] = v;
}

// ---------------- fill CSR: single packed int4 {src, w, eid, 0} per edge -----
__global__ __launch_bounds__(256) void edge_fill(const int* __restrict__ ei,
                                                 const float* __restrict__ ew,
                                                 int* __restrict__ cursor,
                                                 int4* __restrict__ epack) {
    int e = blockIdx.x * 256 + threadIdx.x;
    if (e >= NEDGES) return;
    int src = ei[e];
    int dst = ei[NEDGES + e];
    int pos = atomicAdd(&cursor[dst], 1);
    int4 pk;
    pk.x = src;
    pk.y = __float_as_int(ew[e]);
    pk.z = e;
    pk.w = 0;
    epack[pos] = pk;
}

// ---------------- S[n,11], wsum[n] via CSR segmented sum ---------------------
__global__ __launch_bounds__(256) void node_S(const float* __restrict__ eattr,
                                              const int* __restrict__ rowptr,
                                              const int4* __restrict__ epack,
                                              float* __restrict__ S,
                                              float* __restrict__ wsum) {
    int t = threadIdx.x;
    int j = t & 15, grp = t >> 4;
    int node = blockIdx.x * 16 + grp;
    if (node >= NNODES) return;
    int b = rowptr[node], e = rowptr[node + 1];
    float s = 0.f;
    for (int p = b; p < e; p++) {
        int4 pk = epack[p];
        float w = __int_as_float(pk.y);
        int eid = pk.z;
        if (j < 11) s += eattr[eid * 11 + j] * w;
        else if (j == 11) s += w;
    }
    if (j < 11) S[node * 11 + j] = s;
    else if (j == 11) wsum[node] = s;
}

// ---------------- encoder: h0 = x @ W_atom + b_atom -> hi/lo planes ----------
__global__ __launch_bounds__(256) void enc_atom(const float* __restrict__ X,
                                                const float* __restrict__ W,
                                                const float* __restrict__ b,
                                                short* __restrict__ Hhi,
                                                short* __restrict__ Hlo) {
    __shared__ float as[32 * 48];
    int row0 = blockIdx.x * 32;
    int t = threadIdx.x;
    for (int i = t; i < 32 * 48; i += 256) {
        int r = i / 48, c = i - r * 48;
        int gr = row0 + r;
        as[i] = (gr < NNODES) ? X[gr * 48 + c] : 0.f;
    }
    __syncthreads();
    int c = t & 127, rh = t >> 7;
    float acc[16];
#pragma unroll
    for (int i = 0; i < 16; i++) acc[i] = 0.f;
    for (int k = 0; k < 48; k++) {
        float w = W[k * 128 + c];
#pragma unroll
        for (int i = 0; i < 16; i++) acc[i] += as[(rh * 16 + i) * 48 + k] * w;
    }
    float bb = b[c];
    for (int i = 0; i < 16; i++) {
        int gr = row0 + rh * 16 + i;
        if (gr < NNODES) {
            float v = acc[i] + bb;
            short hi = f2bf(v);
            Hhi[(size_t)gr * 128 + c] = hi;
            Hlo[(size_t)gr * 128 + c] = f2bf(v - bf2f(hi));
        }
    }
}

// ---------------- eagg = S @ W_bond + b_bond * wsum  (K=11) ------------------
__global__ __launch_bounds__(256) void enc_bond(const float* __restrict__ S,
                                                const float* __restrict__ W,
                                                const float* __restrict__ b,
                                                const float* __restrict__ wsum,
                                                float* __restrict__ EA) {
    __shared__ float as[32 * 11];
    __shared__ float wss[32];
    int row0 = blockIdx.x * 32;
    int t = threadIdx.x;
    for (int i = t; i < 32 * 11; i += 256) {
        int r = i / 11, c = i - r * 11;
        int gr = row0 + r;
        as[i] = (gr < NNODES) ? S[gr * 11 + c] : 0.f;
    }
    if (t < 32) wss[t] = (row0 + t < NNODES) ? wsum[row0 + t] : 0.f;
    __syncthreads();
    int c = t & 127, rh = t >> 7;
    float acc[16];
#pragma unroll
    for (int i = 0; i < 16; i++) acc[i] = 0.f;
    for (int k = 0; k < 11; k++) {
        float w = W[k * 128 + c];
#pragma unroll
        for (int i = 0; i < 16; i++) acc[i] += as[(rh * 16 + i) * 11 + k] * w;
    }
    float bb = b[c];
    for (int i = 0; i < 16; i++) {
        int gr = row0 + rh * 16 + i;
        if (gr < NNODES) EA[gr * 128 + c] = acc[i] + bb * wss[rh * 16 + i];
    }
}

// ---------------- per-layer aggregation: bf16-hi gather -> agg hi/lo planes --
__global__ __launch_bounds__(256) void agg_kernel(const short* __restrict__ Hhi,
                                                  const float* __restrict__ eagg,
                                                  const int* __restrict__ rowptr,
                                                  const int4* __restrict__ epack,
                                                  short* __restrict__ Ahi,
                                                  short* __restrict__ Alo) {
    int t = threadIdx.x;
    int lane = t & 31, grp = t >> 5;
    int c4 = lane * 4;
    int node = blockIdx.x * 8 + grp;
    if (node >= NNODES) return;
    int b = rowptr[node], e = rowptr[node + 1];
    float4 s = {0.f, 0.f, 0.f, 0.f};
    int p = b;
    for (; p + 1 < e; p += 2) {
        int4 p0 = epack[p], p1 = epack[p + 1];
        float w0 = __int_as_float(p0.y), w1 = __int_as_float(p1.y);
        ushort4 h0 = *(const ushort4*)&Hhi[(size_t)p0.x * 128 + c4];
        ushort4 h1 = *(const ushort4*)&Hhi[(size_t)p1.x * 128 + c4];
        s.x += bf2f(h0.x) * w0 + bf2f(h1.x) * w1;
        s.y += bf2f(h0.y) * w0 + bf2f(h1.y) * w1;
        s.z += bf2f(h0.z) * w0 + bf2f(h1.z) * w1;
        s.w += bf2f(h0.w) * w0 + bf2f(h1.w) * w1;
    }
    if (p < e) {
        int4 p0 = epack[p];
        float w0 = __int_as_float(p0.y);
        ushort4 h0 = *(const ushort4*)&Hhi[(size_t)p0.x * 128 + c4];
        s.x += bf2f(h0.x) * w0;
        s.y += bf2f(h0.y) * w0;
        s.z += bf2f(h0.z) * w0;
        s.w += bf2f(h0.w) * w0;
    }
    float inv = 1.f / fmaxf((float)(e - b), 1.f);
    float4 ea = *(const float4*)&eagg[(size_t)node * 128 + c4];
    float vf[4] = {(s.x + ea.x) * inv, (s.y + ea.y) * inv,
                   (s.z + ea.z) * inv, (s.w + ea.w) * inv};
    ushort4 hi4, lo4;
    short h;
    h = f2bf(vf[0]); hi4.x = h; lo4.x = f2bf(vf[0] - bf2f(h));
    h = f2bf(vf[1]); hi4.y = h; lo4.y = f2bf(vf[1] - bf2f(h));
    h = f2bf(vf[2]); hi4.z = h; lo4.z = f2bf(vf[2] - bf2f(h));
    h = f2bf(vf[3]); hi4.w = h; lo4.w = f2bf(vf[3] - bf2f(h));
    *(ushort4*)&Ahi[(size_t)node * 128 + c4] = hi4;
    *(ushort4*)&Alo[(size_t)node * 128 + c4] = lo4;
}

// ---------------- weight prep: hi/lo bf16 fragment-layout planes -------------
__global__ __launch_bounds__(256) void bprep(const float* __restrict__ Wl,
                                             const float* __restrict__ Wr,
                                             short* __restrict__ Bf) {
    int idx = blockIdx.x * 256 + threadIdx.x;
    if (idx >= NLAYERS * 32768) return;
    int layer = idx >> 15;
    int r = idx & 32767;
    int k = r >> 7, col = r & 127;
    float w = (k < 128) ? Wl[layer * 16384 + k * 128 + col]
                        : Wr[layer * 16384 + (k - 128) * 128 + col];
    short hi = f2bf(w);
    short lo = f2bf(w - bf2f(hi));
    int kstep = k >> 5, quad = (k >> 3) & 3, j = k & 7;
    int ntile = col >> 4, n = col & 15;
    int fo = ((ntile * 4 + quad) * 16 + n) * 8 + j;
    short* base = Bf + (size_t)layer * 65536 + kstep * 8192;
    base[fo] = hi;
    base[4096 + fo] = lo;
}

// ---------------- MFMA GEMM: C = [agg|h] @ Bf + bias, fused BN stats ---------
// Wave tile 16 rows x 64 cols (4 ntiles); block 32 rows x 128 cols; grid 1563.
// Register double-buffer: prefetch kstep+1's A+B fragments before kstep's MFMAs.
__global__ __launch_bounds__(256, 3) void layer_gemm(const short* __restrict__ Ahi,
                                                     const short* __restrict__ Alo,
                                                     const short* __restrict__ Hhi,
                                                     const short* __restrict__ Hlo,
                                                     const short* __restrict__ Bf,
                                                     const float* __restrict__ bias,
                                                     float* __restrict__ C,
                                                     float* __restrict__ stat) {
    __shared__ float s_s[128], s_q[128];
    int t = threadIdx.x;
    int wave = t >> 6, lane = t & 63;
    int n = lane & 15, quad = lane >> 4;
    int row0 = blockIdx.x * 32;
    int r0 = row0 + (wave >> 1) * 16;      // this wave's 16 rows
    int colbase = (wave & 1) * 64;         // this wave's 64 cols

    if (t < 128) { s_s[t] = 0.f; s_q[t] = 0.f; }
    __syncthreads();

    int myrow = r0 + n;
    bool rowok = myrow < NNODES;
    size_t rbase = (size_t)myrow * 128;

    f32x4 acc[4];
#pragma unroll
    for (int i = 0; i < 4; i++) acc[i] = (f32x4){0.f, 0.f, 0.f, 0.f};

    // lane's base into Bf fragment layout: ntile*512 + quad*128 + n*8
    const short* bb0 = Bf + (colbase >> 4) * 512 + quad * 128 + n * 8;

    s16x8 ah = {0, 0, 0, 0, 0, 0, 0, 0}, al = {0, 0, 0, 0, 0, 0, 0, 0};
    s16x8 bh[4], bl[4];
    // prologue: kstep 0
    if (rowok) {
        ah = *(const s16x8*)(Ahi + rbase + quad * 8);
        al = *(const s16x8*)(Alo + rbase + quad * 8);
    }
#pragma unroll
    for (int nt = 0; nt < 4; nt++) {
        bh[nt] = *(const s16x8*)(bb0 + nt * 512);
        bl[nt] = *(const s16x8*)(bb0 + 4096 + nt * 512);
    }

#pragma unroll
    for (int ks = 0; ks < 8; ks++) {
        s16x8 ah2 = {0, 0, 0, 0, 0, 0, 0, 0}, al2 = {0, 0, 0, 0, 0, 0, 0, 0};
        s16x8 bh2[4], bl2[4];
        if (ks < 7) {
            int kn = ks + 1;
            if (rowok) {
                const short* hs = (kn < 4 ? Ahi : Hhi) + rbase + (kn & 3) * 32 + quad * 8;
                const short* ls = (kn < 4 ? Alo : Hlo) + rbase + (kn & 3) * 32 + quad * 8;
                ah2 = *(const s16x8*)hs;
                al2 = *(const s16x8*)ls;
            }
            const short* bbn = bb0 + kn * 8192;
#pragma unroll
            for (int nt = 0; nt < 4; nt++) {
                bh2[nt] = *(const s16x8*)(bbn + nt * 512);
                bl2[nt] = *(const s16x8*)(bbn + 4096 + nt * 512);
            }
        }
#pragma unroll
        for (int nt = 0; nt < 4; nt++) {
            acc[nt] = __builtin_amdgcn_mfma_f32_16x16x32_bf16(ah, bh[nt], acc[nt], 0, 0, 0);
            acc[nt] = __builtin_amdgcn_mfma_f32_16x16x32_bf16(al, bh[nt], acc[nt], 0, 0, 0);
            acc[nt] = __builtin_amdgcn_mfma_f32_16x16x32_bf16(ah, bl[nt], acc[nt], 0, 0, 0);
        }
        if (ks < 7) {
            ah = ah2;
            al = al2;
#pragma unroll
            for (int nt = 0; nt < 4; nt++) {
                bh[nt] = bh2[nt];
                bl[nt] = bl2[nt];
            }
        }
    }

#pragma unroll
    for (int nt = 0; nt < 4; nt++) {
        int col = colbase + nt * 16 + n;
        float bb = bias[col];
        float ss = 0.f, qq = 0.f;
#pragma unroll
        for (int reg = 0; reg < 4; reg++) {
            int r = r0 + quad * 4 + reg;
            if (r < NNODES) {
                float v = acc[nt][reg] + bb;
                C[(size_t)r * 128 + col] = v;
                ss += v;
                qq += v * v;
            }
        }
        ss += __shfl_xor(ss, 16);
        ss += __shfl_xor(ss, 32);
        qq += __shfl_xor(qq, 16);
        qq += __shfl_xor(qq, 32);
        if (quad == 0) {
            atomicAdd(&s_s[col], ss);
            atomicAdd(&s_q[col], qq);
        }
    }
    __syncthreads();
    if (t < 128) {
        atomicAdd(&stat[t], s_s[t]);
        atomicAdd(&stat[128 + t], s_q[t]);
    }
}

// ---------------- BN apply (+inline coef) + ReLU + xpool ---------------------
__global__ __launch_bounds__(256) void bn_apply(const float* __restrict__ Hin,
                                                short* __restrict__ Hhi,
                                                short* __restrict__ Hlo,
                                                float* __restrict__ Hf32,
                                                const float* __restrict__ stat,
                                                const float* __restrict__ gamma,
                                                const float* __restrict__ beta,
                                                const int* __restrict__ batch,
                                                float* __restrict__ pool,
                                                int layer, int relu) {
    __shared__ float csc[128], csh[128];
    int t = threadIdx.x;
    if (t < 128) {
        const float invM = 1.f / (float)NNODES;
        float mu = stat[t] * invM;
        float var = stat[128 + t] * invM - mu * mu;
        float inv = rsqrtf(var + BN_EPS);
        float sc = gamma[t] * inv;
        csc[t] = sc;
        csh[t] = beta[t] - mu * sc;
    }
    __syncthreads();
    int lane = t & 31, grp = t >> 5;
    int c4 = lane * 4;
    float4 sc = *(const float4*)&csc[c4];
    float4 sh = *(const float4*)&csh[c4];
    int row0 = blockIdx.x * 256;
    float4 accp = {0.f, 0.f, 0.f, 0.f};
    int curg = -1;
    float* pbase = pool + layer * 128 + c4;
    for (int rr = grp; rr < 256; rr += 8) {
        int r = row0 + rr;
        if (r >= NNODES) break;
        float4 v = *(const float4*)&Hin[(size_t)r * 128 + c4];
        v.x = v.x * sc.x + sh.x;
        v.y = v.y * sc.y + sh.y;
        v.z = v.z * sc.z + sh.z;
        v.w = v.w * sc.w + sh.w;
        if (relu) {
            v.x = fmaxf(v.x, 0.f);
            v.y = fmaxf(v.y, 0.f);
            v.z = fmaxf(v.z, 0.f);
            v.w = fmaxf(v.w, 0.f);
        }
        if (Hf32) {
            *(float4*)&Hf32[(size_t)r * 128 + c4] = v;
        } else {
            float vf[4] = {v.x, v.y, v.z, v.w};
            ushort4 hi4, lo4;
            short h;
            h = f2bf(vf[0]); hi4.x = h; lo4.x = f2bf(vf[0] - bf2f(h));
            h = f2bf(vf[1]); hi4.y = h; lo4.y = f2bf(vf[1] - bf2f(h));
            h = f2bf(vf[2]); hi4.z = h; lo4.z = f2bf(vf[2] - bf2f(h));
            h = f2bf(vf[3]); hi4.w = h; lo4.w = f2bf(vf[3] - bf2f(h));
            *(ushort4*)&Hhi[(size_t)r * 128 + c4] = hi4;
            *(ushort4*)&Hlo[(size_t)r * 128 + c4] = lo4;
        }
        int g = batch[r];
        if (g != curg) {
            if (curg >= 0) {
                float* p = pbase + curg * 640;
                atomicAdd(p + 0, accp.x);
                atomicAdd(p + 1, accp.y);
                atomicAdd(p + 2, accp.z);
                atomicAdd(p + 3, accp.w);
            }
            curg = g;
            accp.x = accp.y = accp.z = accp.w = 0.f;
        }
        accp.x += v.x;
        accp.y += v.y;
        accp.z += v.z;
        accp.w += v.w;
    }
    if (curg >= 0) {
        float* p = pbase + curg * 640;
        atomicAdd(p + 0, accp.x);
        atomicAdd(p + 1, accp.y);
        atomicAdd(p + 2, accp.z);
        atomicAdd(p + 3, accp.w);
    }
}

extern "C" void kernel_launch(void* const* d_in, const int* in_sizes, int n_in,
                              void* d_out, int out_size, void* d_ws, size_t ws_size,
                              hipStream_t stream) {
    const int* batch = (const int*)d_in[0];
    const float* x = (const float*)d_in[1];
    const int* edge_index = (const int*)d_in[2];
    const float* edge_attr = (const float*)d_in[3];
    const float* edge_weight = (const float*)d_in[4];
    const float* W_atom = (const float*)d_in[5];
    const float* b_atom = (const float*)d_in[6];
    const float* W_bond = (const float*)d_in[7];
    const float* b_bond = (const float*)d_in[8];
    const float* Wl = (const float*)d_in[9];
    const float* bl = (const float*)d_in[10];
    const float* Wr = (const float*)d_in[11];
    const float* gamma = (const float*)d_in[12];
    const float* beta = (const float*)d_in[13];
    float* out = (float*)d_out;

    // ---- workspace layout ----
    char* ws = (char*)d_ws;
    size_t off = 0;
    auto alloc = [&](size_t bytes) -> void* {
        void* p = ws + off;
        off += (bytes + 255) & ~(size_t)255;
        return p;
    };
    short* Hhi = (short*)alloc((size_t)NNODES * 128 * 2);
    short* Hlo = (short*)alloc((size_t)NNODES * 128 * 2);
    short* Ahi = (short*)alloc((size_t)NNODES * 128 * 2);
    short* Alo = (short*)alloc((size_t)NNODES * 128 * 2);
    float* hB = (float*)alloc((size_t)NNODES * 128 * 4);
    float* eagg = (float*)alloc((size_t)NNODES * 128 * 4);
    int4* epack = (int4*)alloc((size_t)NEDGES * 16);
    int* rowptr = (int*)alloc((size_t)(NNODES + 1) * 4);
    int* cursor = (int*)alloc((size_t)NNODES * 4);
    int* deg = (int*)alloc((size_t)NNODES * 4);
    float* wsum = (float*)alloc((size_t)NNODES * 4);
    float* S = (float*)alloc((size_t)NNODES * 11 * 4);
    float* stat = (float*)alloc(NLAYERS * 256 * 4);
    int* local_excl = (int*)alloc((size_t)NNODES * 4);
    int* part = (int*)alloc(SCAN_BLOCKS * 4);
    int* blockoff = (int*)alloc(SCAN_BLOCKS * 4);
    short* Bf = (short*)alloc((size_t)NLAYERS * 65536 * 2);

    // ---- zero-init accumulation buffers ----
    hipMemsetAsync(out, 0, (size_t)NGRAPHS * 640 * 4, stream);
    hipMemsetAsync(deg, 0, (size_t)NNODES * 4, stream);
    hipMemsetAsync(stat, 0, NLAYERS * 256 * 4, stream);

    // ---- preprocessing ----
    deg_kernel<<<(NEDGES + 255) / 256, 256, 0, stream>>>(edge_index, deg);
    scan1<<<SCAN_BLOCKS, 256, 0, stream>>>(deg, local_excl, part);
    scan2<<<1, 256, 0, stream>>>(part, blockoff, rowptr);
    scan3<<<SCAN_BLOCKS, 256, 0, stream>>>(local_excl, blockoff, rowptr, cursor);
    edge_fill<<<(NEDGES + 255) / 256, 256, 0, stream>>>(edge_index, edge_weight, cursor,
                                                        epack);
    node_S<<<(NNODES + 15) / 16, 256, 0, stream>>>(edge_attr, rowptr, epack, S, wsum);
    bprep<<<(NLAYERS * 32768 + 255) / 256, 256, 0, stream>>>(Wl, Wr, Bf);
    enc_atom<<<(NNODES + 31) / 32, 256, 0, stream>>>(x, W_atom, b_atom, Hhi, Hlo);
    enc_bond<<<(NNODES + 31) / 32, 256, 0, stream>>>(S, W_bond, b_bond, wsum, eagg);

    // ---- layers ----
    for (int i = 0; i < NLAYERS; i++) {
        agg_kernel<<<(NNODES + 7) / 8, 256, 0, stream>>>(Hhi, eagg, rowptr, epack,
                                                         Ahi, Alo);
        layer_gemm<<<(NNODES + 31) / 32, 256, 0, stream>>>(Ahi, Alo, Hhi, Hlo,
                                                           Bf + (size_t)i * 65536,
                                                           bl + i * 128, hB,
                                                           stat + i * 256);
        int last = (i == NLAYERS - 1);
        bn_apply<<<(NNODES + 255) / 256, 256, 0, stream>>>(
            hB, Hhi, Hlo, last ? (out + (size_t)NGRAPHS * 640) : nullptr,
            stat + i * 256, gamma + i * 128, beta + i * 128, batch, out, i,
            last ? 0 : 1);
    }
}

// Round 8
// 745.270 us; speedup vs baseline: 1.1506x; 1.1506x over previous
//
#include <hip/hip_runtime.h>
#include <hip/hip_bf16.h>

#define NNODES 50000
#define NEDGES 600000
#define NGRAPHS 128
#define EMB 128
#define NLAYERS 5
#define BN_EPS 1e-5f
#define SCAN_BLOCKS ((NNODES + 255) / 256)  // 196

typedef short s16x8 __attribute__((ext_vector_type(8)));
typedef float f32x4 __attribute__((ext_vector_type(4)));
typedef float f32x16 __attribute__((ext_vector_type(16)));

__device__ __forceinline__ short f2bf(float f) {
    unsigned u = __builtin_bit_cast(unsigned, f);
    unsigned r = (u + 0x7fffu + ((u >> 16) & 1u)) >> 16;  // RNE
    return (short)r;
}
__device__ __forceinline__ float bf2f(short s) {
    return __builtin_bit_cast(float, ((unsigned)(unsigned short)s) << 16);
}

// ---------------- deg histogram (int atomics only) ---------------------------
__global__ __launch_bounds__(256) void deg_kernel(const int* __restrict__ ei,
                                                  int* __restrict__ deg) {
    int e = blockIdx.x * 256 + threadIdx.x;
    if (e >= NEDGES) return;
    atomicAdd(&deg[ei[NEDGES + e]], 1);
}

// ---------------- multi-block scan ------------------------------------------
__global__ __launch_bounds__(256) void scan1(const int* __restrict__ deg,
                                             int* __restrict__ local_excl,
                                             int* __restrict__ part) {
    __shared__ int sh[256];
    int t = threadIdx.x;
    int i = blockIdx.x * 256 + t;
    int v = (i < NNODES) ? deg[i] : 0;
    sh[t] = v;
    __syncthreads();
    for (int off = 1; off < 256; off <<= 1) {
        int u = (t >= off) ? sh[t - off] : 0;
        __syncthreads();
        sh[t] += u;
        __syncthreads();
    }
    if (i < NNODES) local_excl[i] = sh[t] - v;
    if (t == 255) part[blockIdx.x] = sh[255];
}

__global__ __launch_bounds__(256) void scan2(int* __restrict__ part,
                                             int* __restrict__ blockoff,
                                             int* __restrict__ rowptr) {
    __shared__ int sh[256];
    int t = threadIdx.x;
    int v = (t < SCAN_BLOCKS) ? part[t] : 0;
    sh[t] = v;
    __syncthreads();
    for (int off = 1; off < 256; off <<= 1) {
        int u = (t >= off) ? sh[t - off] : 0;
        __syncthreads();
        sh[t] += u;
        __syncthreads();
    }
    if (t < SCAN_BLOCKS) blockoff[t] = sh[t] - v;
    if (t == 255) rowptr[NNODES] = sh[255];
}

__global__ __launch_bounds__(256) void scan3(const int* __restrict__ local_excl,
                                             const int* __restrict__ blockoff,
                                             int* __restrict__ rowptr,
                                             int* __restrict__ cursor) {
    int i = blockIdx.x * 256 + threadIdx.x;
    if (i >= NNODES) return;
    int v = local_excl[i] + blockoff[blockIdx.x];
    rowptr[i] = v;
    cursor[i] = v;
}

// ---------------- fill CSR: single packed int4 {src, w, eid, 0} per edge -----
__global__ __launch_bounds__(256) void edge_fill(const int* __restrict__ ei,
                                                 const float* __restrict__ ew,
                                                 int* __restrict__ cursor,
                                                 int4* __restrict__ epack) {
    int e = blockIdx.x * 256 + threadIdx.x;
    if (e >= NEDGES) return;
    int src = ei[e];
    int dst = ei[NEDGES + e];
    int pos = atomicAdd(&cursor[dst], 1);
    int4 pk;
    pk.x = src;
    pk.y = __float_as_int(ew[e]);
    pk.z = e;
    pk.w = 0;
    epack[pos] = pk;
}

// ---------------- S[n,11], wsum[n] via CSR segmented sum ---------------------
__global__ __launch_bounds__(256) void node_S(const float* __restrict__ eattr,
                                              const int* __restrict__ rowptr,
                                              const int4* __restrict__ epack,
                                              float* __restrict__ S,
                                              float* __restrict__ wsum) {
    int t = threadIdx.x;
    int j = t & 15, grp = t >> 4;
    int node = blockIdx.x * 16 + grp;
    if (node >= NNODES) return;
    int b = rowptr[node], e = rowptr[node + 1];
    float s = 0.f;
    for (int p = b; p < e; p++) {
        int4 pk = epack[p];
        float w = __int_as_float(pk.y);
        int eid = pk.z;
        if (j < 11) s += eattr[eid * 11 + j] * w;
        else if (j == 11) s += w;
    }
    if (j < 11) S[node * 11 + j] = s;
    else if (j == 11) wsum[node] = s;
}

// ---------------- encoder: h0 = x @ W_atom + b_atom -> hi/lo planes ----------
__global__ __launch_bounds__(256) void enc_atom(const float* __restrict__ X,
                                                const float* __restrict__ W,
                                                const float* __restrict__ b,
                                                short* __restrict__ Hhi,
                                                short* __restrict__ Hlo) {
    __shared__ float as[32 * 48];
    int row0 = blockIdx.x * 32;
    int t = threadIdx.x;
    for (int i = t; i < 32 * 48; i += 256) {
        int r = i / 48, c = i - r * 48;
        int gr = row0 + r;
        as[i] = (gr < NNODES) ? X[gr * 48 + c] : 0.f;
    }
    __syncthreads();
    int c = t & 127, rh = t >> 7;
    float acc[16];
#pragma unroll
    for (int i = 0; i < 16; i++) acc[i] = 0.f;
    for (int k = 0; k < 48; k++) {
        float w = W[k * 128 + c];
#pragma unroll
        for (int i = 0; i < 16; i++) acc[i] += as[(rh * 16 + i) * 48 + k] * w;
    }
    float bb = b[c];
    for (int i = 0; i < 16; i++) {
        int gr = row0 + rh * 16 + i;
        if (gr < NNODES) {
            float v = acc[i] + bb;
            short hi = f2bf(v);
            Hhi[(size_t)gr * 128 + c] = hi;
            Hlo[(size_t)gr * 128 + c] = f2bf(v - bf2f(hi));
        }
    }
}

// ---------------- eagg = S @ W_bond + b_bond * wsum  (K=11) ------------------
__global__ __launch_bounds__(256) void enc_bond(const float* __restrict__ S,
                                                const float* __restrict__ W,
                                                const float* __restrict__ b,
                                                const float* __restrict__ wsum,
                                                float* __restrict__ EA) {
    __shared__ float as[32 * 11];
    __shared__ float wss[32];
    int row0 = blockIdx.x * 32;
    int t = threadIdx.x;
    for (int i = t; i < 32 * 11; i += 256) {
        int r = i / 11, c = i - r * 11;
        int gr = row0 + r;
        as[i] = (gr < NNODES) ? S[gr * 11 + c] : 0.f;
    }
    if (t < 32) wss[t] = (row0 + t < NNODES) ? wsum[row0 + t] : 0.f;
    __syncthreads();
    int c = t & 127, rh = t >> 7;
    float acc[16];
#pragma unroll
    for (int i = 0; i < 16; i++) acc[i] = 0.f;
    for (int k = 0; k < 11; k++) {
        float w = W[k * 128 + c];
#pragma unroll
        for (int i = 0; i < 16; i++) acc[i] += as[(rh * 16 + i) * 11 + k] * w;
    }
    float bb = b[c];
    for (int i = 0; i < 16; i++) {
        int gr = row0 + rh * 16 + i;
        if (gr < NNODES) EA[gr * 128 + c] = acc[i] + bb * wss[rh * 16 + i];
    }
}

// ---------------- per-layer aggregation: bf16-hi gather -> agg hi/lo planes --
__global__ __launch_bounds__(256) void agg_kernel(const short* __restrict__ Hhi,
                                                  const float* __restrict__ eagg,
                                                  const int* __restrict__ rowptr,
                                                  const int4* __restrict__ epack,
                                                  short* __restrict__ Ahi,
                                                  short* __restrict__ Alo) {
    int t = threadIdx.x;
    int lane = t & 31, grp = t >> 5;
    int c4 = lane * 4;
    int node = blockIdx.x * 8 + grp;
    if (node >= NNODES) return;
    int b = rowptr[node], e = rowptr[node + 1];
    float4 s = {0.f, 0.f, 0.f, 0.f};
    int p = b;
    for (; p + 1 < e; p += 2) {
        int4 p0 = epack[p], p1 = epack[p + 1];
        float w0 = __int_as_float(p0.y), w1 = __int_as_float(p1.y);
        ushort4 h0 = *(const ushort4*)&Hhi[(size_t)p0.x * 128 + c4];
        ushort4 h1 = *(const ushort4*)&Hhi[(size_t)p1.x * 128 + c4];
        s.x += bf2f(h0.x) * w0 + bf2f(h1.x) * w1;
        s.y += bf2f(h0.y) * w0 + bf2f(h1.y) * w1;
        s.z += bf2f(h0.z) * w0 + bf2f(h1.z) * w1;
        s.w += bf2f(h0.w) * w0 + bf2f(h1.w) * w1;
    }
    if (p < e) {
        int4 p0 = epack[p];
        float w0 = __int_as_float(p0.y);
        ushort4 h0 = *(const ushort4*)&Hhi[(size_t)p0.x * 128 + c4];
        s.x += bf2f(h0.x) * w0;
        s.y += bf2f(h0.y) * w0;
        s.z += bf2f(h0.z) * w0;
        s.w += bf2f(h0.w) * w0;
    }
    float inv = 1.f / fmaxf((float)(e - b), 1.f);
    float4 ea = *(const float4*)&eagg[(size_t)node * 128 + c4];
    float vf[4] = {(s.x + ea.x) * inv, (s.y + ea.y) * inv,
                   (s.z + ea.z) * inv, (s.w + ea.w) * inv};
    ushort4 hi4, lo4;
    short h;
    h = f2bf(vf[0]); hi4.x = h; lo4.x = f2bf(vf[0] - bf2f(h));
    h = f2bf(vf[1]); hi4.y = h; lo4.y = f2bf(vf[1] - bf2f(h));
    h = f2bf(vf[2]); hi4.z = h; lo4.z = f2bf(vf[2] - bf2f(h));
    h = f2bf(vf[3]); hi4.w = h; lo4.w = f2bf(vf[3] - bf2f(h));
    *(ushort4*)&Ahi[(size_t)node * 128 + c4] = hi4;
    *(ushort4*)&Alo[(size_t)node * 128 + c4] = lo4;
}

// ---------------- weight prep for 32x32x16 fragments -------------------------
// Bf per layer: 16 kstep blocks of 4096 shorts = [hi 2048 | lo 2048].
// Within plane: fo = ((nt*2 + half)*32 + n32)*8 + j, where
// k = ks*16 + half*8 + j, col = nt*32 + n32.
__global__ __launch_bounds__(256) void bprep(const float* __restrict__ Wl,
                                             const float* __restrict__ Wr,
                                             short* __restrict__ Bf) {
    int idx = blockIdx.x * 256 + threadIdx.x;
    if (idx >= NLAYERS * 32768) return;
    int layer = idx >> 15;
    int r = idx & 32767;
    int k = r >> 7, col = r & 127;
    float w = (k < 128) ? Wl[layer * 16384 + k * 128 + col]
                        : Wr[layer * 16384 + (k - 128) * 128 + col];
    short hi = f2bf(w);
    short lo = f2bf(w - bf2f(hi));
    int ks = k >> 4, half = (k >> 3) & 1, j = k & 7;
    int nt = col >> 5, n32 = col & 31;
    int fo = ((nt * 2 + half) * 32 + n32) * 8 + j;
    short* base = Bf + (size_t)layer * 65536 + ks * 4096;
    base[fo] = hi;
    base[2048 + fo] = lo;
}

// ---------------- MFMA GEMM (32x32x16): C = [agg|h] @ Bf + bias, BN stats ----
// Wave tile 32 rows x 128 cols (4 ntiles of 32). Block = 4 waves = 128 rows.
// Register double-buffer: kstep k+1's A+B fragments prefetched before k's MFMAs.
__global__ __launch_bounds__(256) void layer_gemm(const short* __restrict__ Ahi,
                                                  const short* __restrict__ Alo,
                                                  const short* __restrict__ Hhi,
                                                  const short* __restrict__ Hlo,
                                                  const short* __restrict__ Bf,
                                                  const float* __restrict__ bias,
                                                  float* __restrict__ C,
                                                  float* __restrict__ stat) {
    __shared__ float s_s[128], s_q[128];
    int t = threadIdx.x;
    int wave = t >> 6, lane = t & 63;
    int n32 = lane & 31, half = lane >> 5;
    int row0 = blockIdx.x * 128 + wave * 32;   // this wave's 32 rows

    if (t < 128) { s_s[t] = 0.f; s_q[t] = 0.f; }
    __syncthreads();

    int myrow = row0 + n32;                    // A row for this lane
    bool rowok = myrow < NNODES;
    size_t rbase = (size_t)myrow * 128;
    int acol = half * 8;                       // A col offset within kstep

    f32x16 acc[4];
#pragma unroll
    for (int i = 0; i < 4; i++) acc[i] = (f32x16)(0.f);

    // lane's base into Bf fragment layout (shorts): (nt*2+half)*256 + n32*8
    const short* bb0 = Bf + half * 256 + n32 * 8;

    s16x8 ah = {0, 0, 0, 0, 0, 0, 0, 0}, al = {0, 0, 0, 0, 0, 0, 0, 0};
    s16x8 bh[4], bl[4];
    // prologue: kstep 0 (agg, cols [0,16))
    if (rowok) {
        ah = *(const s16x8*)(Ahi + rbase + acol);
        al = *(const s16x8*)(Alo + rbase + acol);
    }
#pragma unroll
    for (int nt = 0; nt < 4; nt++) {
        bh[nt] = *(const s16x8*)(bb0 + nt * 512);
        bl[nt] = *(const s16x8*)(bb0 + 2048 + nt * 512);
    }

#pragma unroll
    for (int ks = 0; ks < 16; ks++) {
        s16x8 ah2 = {0, 0, 0, 0, 0, 0, 0, 0}, al2 = {0, 0, 0, 0, 0, 0, 0, 0};
        s16x8 bh2[4], bl2[4];
        if (ks < 15) {
            int kn = ks + 1;
            if (rowok) {
                const short* hs = (kn < 8 ? Ahi : Hhi) + rbase + (kn & 7) * 16 + acol;
                const short* ls = (kn < 8 ? Alo : Hlo) + rbase + (kn & 7) * 16 + acol;
                ah2 = *(const s16x8*)hs;
                al2 = *(const s16x8*)ls;
            }
            const short* bbn = bb0 + kn * 4096;
#pragma unroll
            for (int nt = 0; nt < 4; nt++) {
                bh2[nt] = *(const s16x8*)(bbn + nt * 512);
                bl2[nt] = *(const s16x8*)(bbn + 2048 + nt * 512);
            }
        }
#pragma unroll
        for (int nt = 0; nt < 4; nt++) {
            acc[nt] = __builtin_amdgcn_mfma_f32_32x32x16_bf16(ah, bh[nt], acc[nt], 0, 0, 0);
            acc[nt] = __builtin_amdgcn_mfma_f32_32x32x16_bf16(al, bh[nt], acc[nt], 0, 0, 0);
            acc[nt] = __builtin_amdgcn_mfma_f32_32x32x16_bf16(ah, bl[nt], acc[nt], 0, 0, 0);
        }
        if (ks < 15) {
            ah = ah2;
            al = al2;
#pragma unroll
            for (int nt = 0; nt < 4; nt++) {
                bh[nt] = bh2[nt];
                bl[nt] = bl2[nt];
            }
        }
    }

    // epilogue: bias, C write, fused BN partial stats
    // C/D layout: col = nt*32 + n32, row = row0 + (reg&3) + 8*(reg>>2) + 4*half
#pragma unroll
    for (int nt = 0; nt < 4; nt++) {
        int col = nt * 32 + n32;
        float bb = bias[col];
        float ss = 0.f, qq = 0.f;
#pragma unroll
        for (int reg = 0; reg < 16; reg++) {
            int r = row0 + (reg & 3) + 8 * (reg >> 2) + 4 * half;
            if (r < NNODES) {
                float v = acc[nt][reg] + bb;
                C[(size_t)r * 128 + col] = v;
                ss += v;
                qq += v * v;
            }
        }
        ss += __shfl_xor(ss, 32);   // combine the two half-groups (same col)
        qq += __shfl_xor(qq, 32);
        if (half == 0) {
            atomicAdd(&s_s[col], ss);
            atomicAdd(&s_q[col], qq);
        }
    }
    __syncthreads();
    if (t < 128) {
        atomicAdd(&stat[t], s_s[t]);
        atomicAdd(&stat[128 + t], s_q[t]);
    }
}

// ---------------- BN apply (+inline coef) + ReLU + xpool ---------------------
__global__ __launch_bounds__(256) void bn_apply(const float* __restrict__ Hin,
                                                short* __restrict__ Hhi,
                                                short* __restrict__ Hlo,
                                                float* __restrict__ Hf32,
                                                const float* __restrict__ stat,
                                                const float* __restrict__ gamma,
                                                const float* __restrict__ beta,
                                                const int* __restrict__ batch,
                                                float* __restrict__ pool,
                                                int layer, int relu) {
    __shared__ float csc[128], csh[128];
    int t = threadIdx.x;
    if (t < 128) {
        const float invM = 1.f / (float)NNODES;
        float mu = stat[t] * invM;
        float var = stat[128 + t] * invM - mu * mu;
        float inv = rsqrtf(var + BN_EPS);
        float sc = gamma[t] * inv;
        csc[t] = sc;
        csh[t] = beta[t] - mu * sc;
    }
    __syncthreads();
    int lane = t & 31, grp = t >> 5;
    int c4 = lane * 4;
    float4 sc = *(const float4*)&csc[c4];
    float4 sh = *(const float4*)&csh[c4];
    int row0 = blockIdx.x * 256;
    float4 accp = {0.f, 0.f, 0.f, 0.f};
    int curg = -1;
    float* pbase = pool + layer * 128 + c4;
    for (int rr = grp; rr < 256; rr += 8) {
        int r = row0 + rr;
        if (r >= NNODES) break;
        float4 v = *(const float4*)&Hin[(size_t)r * 128 + c4];
        v.x = v.x * sc.x + sh.x;
        v.y = v.y * sc.y + sh.y;
        v.z = v.z * sc.z + sh.z;
        v.w = v.w * sc.w + sh.w;
        if (relu) {
            v.x = fmaxf(v.x, 0.f);
            v.y = fmaxf(v.y, 0.f);
            v.z = fmaxf(v.z, 0.f);
            v.w = fmaxf(v.w, 0.f);
        }
        if (Hf32) {
            *(float4*)&Hf32[(size_t)r * 128 + c4] = v;
        } else {
            float vf[4] = {v.x, v.y, v.z, v.w};
            ushort4 hi4, lo4;
            short h;
            h = f2bf(vf[0]); hi4.x = h; lo4.x = f2bf(vf[0] - bf2f(h));
            h = f2bf(vf[1]); hi4.y = h; lo4.y = f2bf(vf[1] - bf2f(h));
            h = f2bf(vf[2]); hi4.z = h; lo4.z = f2bf(vf[2] - bf2f(h));
            h = f2bf(vf[3]); hi4.w = h; lo4.w = f2bf(vf[3] - bf2f(h));
            *(ushort4*)&Hhi[(size_t)r * 128 + c4] = hi4;
            *(ushort4*)&Hlo[(size_t)r * 128 + c4] = lo4;
        }
        int g = batch[r];
        if (g != curg) {
            if (curg >= 0) {
                float* p = pbase + curg * 640;
                atomicAdd(p + 0, accp.x);
                atomicAdd(p + 1, accp.y);
                atomicAdd(p + 2, accp.z);
                atomicAdd(p + 3, accp.w);
            }
            curg = g;
            accp.x = accp.y = accp.z = accp.w = 0.f;
        }
        accp.x += v.x;
        accp.y += v.y;
        accp.z += v.z;
        accp.w += v.w;
    }
    if (curg >= 0) {
        float* p = pbase + curg * 640;
        atomicAdd(p + 0, accp.x);
        atomicAdd(p + 1, accp.y);
        atomicAdd(p + 2, accp.z);
        atomicAdd(p + 3, accp.w);
    }
}

extern "C" void kernel_launch(void* const* d_in, const int* in_sizes, int n_in,
                              void* d_out, int out_size, void* d_ws, size_t ws_size,
                              hipStream_t stream) {
    const int* batch = (const int*)d_in[0];
    const float* x = (const float*)d_in[1];
    const int* edge_index = (const int*)d_in[2];
    const float* edge_attr = (const float*)d_in[3];
    const float* edge_weight = (const float*)d_in[4];
    const float* W_atom = (const float*)d_in[5];
    const float* b_atom = (const float*)d_in[6];
    const float* W_bond = (const float*)d_in[7];
    const float* b_bond = (const float*)d_in[8];
    const float* Wl = (const float*)d_in[9];
    const float* bl = (const float*)d_in[10];
    const float* Wr = (const float*)d_in[11];
    const float* gamma = (const float*)d_in[12];
    const float* beta = (const float*)d_in[13];
    float* out = (float*)d_out;

    // ---- workspace layout ----
    char* ws = (char*)d_ws;
    size_t off = 0;
    auto alloc = [&](size_t bytes) -> void* {
        void* p = ws + off;
        off += (bytes + 255) & ~(size_t)255;
        return p;
    };
    short* Hhi = (short*)alloc((size_t)NNODES * 128 * 2);
    short* Hlo = (short*)alloc((size_t)NNODES * 128 * 2);
    short* Ahi = (short*)alloc((size_t)NNODES * 128 * 2);
    short* Alo = (short*)alloc((size_t)NNODES * 128 * 2);
    float* hB = (float*)alloc((size_t)NNODES * 128 * 4);
    float* eagg = (float*)alloc((size_t)NNODES * 128 * 4);
    int4* epack = (int4*)alloc((size_t)NEDGES * 16);
    int* rowptr = (int*)alloc((size_t)(NNODES + 1) * 4);
    int* cursor = (int*)alloc((size_t)NNODES * 4);
    int* deg = (int*)alloc((size_t)NNODES * 4);
    float* wsum = (float*)alloc((size_t)NNODES * 4);
    float* S = (float*)alloc((size_t)NNODES * 11 * 4);
    float* stat = (float*)alloc(NLAYERS * 256 * 4);
    int* local_excl = (int*)alloc((size_t)NNODES * 4);
    int* part = (int*)alloc(SCAN_BLOCKS * 4);
    int* blockoff = (int*)alloc(SCAN_BLOCKS * 4);
    short* Bf = (short*)alloc((size_t)NLAYERS * 65536 * 2);

    // ---- zero-init accumulation buffers ----
    hipMemsetAsync(out, 0, (size_t)NGRAPHS * 640 * 4, stream);
    hipMemsetAsync(deg, 0, (size_t)NNODES * 4, stream);
    hipMemsetAsync(stat, 0, NLAYERS * 256 * 4, stream);

    // ---- preprocessing ----
    deg_kernel<<<(NEDGES + 255) / 256, 256, 0, stream>>>(edge_index, deg);
    scan1<<<SCAN_BLOCKS, 256, 0, stream>>>(deg, local_excl, part);
    scan2<<<1, 256, 0, stream>>>(part, blockoff, rowptr);
    scan3<<<SCAN_BLOCKS, 256, 0, stream>>>(local_excl, blockoff, rowptr, cursor);
    edge_fill<<<(NEDGES + 255) / 256, 256, 0, stream>>>(edge_index, edge_weight, cursor,
                                                        epack);
    node_S<<<(NNODES + 15) / 16, 256, 0, stream>>>(edge_attr, rowptr, epack, S, wsum);
    bprep<<<(NLAYERS * 32768 + 255) / 256, 256, 0, stream>>>(Wl, Wr, Bf);
    enc_atom<<<(NNODES + 31) / 32, 256, 0, stream>>>(x, W_atom, b_atom, Hhi, Hlo);
    enc_bond<<<(NNODES + 31) / 32, 256, 0, stream>>>(S, W_bond, b_bond, wsum, eagg);

    // ---- layers ----
    for (int i = 0; i < NLAYERS; i++) {
        agg_kernel<<<(NNODES + 7) / 8, 256, 0, stream>>>(Hhi, eagg, rowptr, epack,
                                                         Ahi, Alo);
        layer_gemm<<<(NNODES + 127) / 128, 256, 0, stream>>>(Ahi, Alo, Hhi, Hlo,
                                                             Bf + (size_t)i * 65536,
                                                             bl + i * 128, hB,
                                                             stat + i * 256);
        int last = (i == NLAYERS - 1);
        bn_apply<<<(NNODES + 255) / 256, 256, 0, stream>>>(
            hB, Hhi, Hlo, last ? (out + (size_t)NGRAPHS * 640) : nullptr,
            stat + i * 256, gamma + i * 128, beta + i * 128, batch, out, i,
            last ? 0 : 1);
    }
}